// Round 9
// baseline (369.622 us; speedup 1.0000x reference)
//
#include <hip/hip_runtime.h>

#define NPIX 9216
#define NL   21
#define WW   96
#define RAD  16
#define JS   16
#define L2E  1.44269504088896340736f

typedef __bf16 bf16x8 __attribute__((ext_vector_type(8)));
typedef float  f32x16 __attribute__((ext_vector_type(16)));

__device__ __forceinline__ float fexp2(float x) { return __builtin_amdgcn_exp2f(x); }
__device__ __forceinline__ unsigned pkbf(float lo, float hi) {
    unsigned r;
    asm("v_cvt_pk_bf16_f32 %0, %1, %2" : "=v"(r) : "v"(lo), "v"(hi));
    return r;
}

// ---------- prep: bf16 feature fragments + truncated spatial norm + QhT const rows ----------
// Fj8[j][16] = [fj*L2E x5, sj', 1, 0...]   (A-side of dot MFMA)
// FiT8[i][16] = [fi x5, -1, -si', 0...]    (B-side)  =>  D = L2E*fi.fj - sj' - si'
__global__ __launch_bounds__(256) void featK(const float* __restrict__ img,
                                             __bf16* __restrict__ FiT8, __bf16* __restrict__ Fj8,
                                             float* __restrict__ norm_s, __bf16* __restrict__ QhT) {
    int i = blockIdx.x * 256 + threadIdx.x;
    if (i >= NPIX) return;
    int y = i / WW, x = i - y * WW;
    float f0 = (float)x * (1.0f / 160.0f);
    float f1 = (float)y * (1.0f / 160.0f);
    float f2 = img[0 * NPIX + i] * (1.0f / 3.0f);
    float f3 = img[1 * NPIX + i] * (1.0f / 3.0f);
    float f4 = img[2 * NPIX + i] * (1.0f / 3.0f);
    float st = 0.5f * (f0*f0 + f1*f1 + f2*f2 + f3*f3 + f4*f4) * L2E;
    __bf16* a = Fj8 + (size_t)i * 16;
    __bf16* b = FiT8 + (size_t)i * 16;
    a[0]=(__bf16)(f0*L2E); a[1]=(__bf16)(f1*L2E); a[2]=(__bf16)(f2*L2E);
    a[3]=(__bf16)(f3*L2E); a[4]=(__bf16)(f4*L2E); a[5]=(__bf16)st; a[6]=(__bf16)1.0f;
    b[0]=(__bf16)f0; b[1]=(__bf16)f1; b[2]=(__bf16)f2; b[3]=(__bf16)f3; b[4]=(__bf16)f4;
    b[5]=(__bf16)-1.0f; b[6]=(__bf16)(-st);
    #pragma unroll
    for (int k = 7; k < 16; k++) { a[k] = (__bf16)0.0f; b[k] = (__bf16)0.0f; }
    QhT[(size_t)21 * NPIX + i] = (__bf16)1.0f;
    #pragma unroll
    for (int l = 22; l < 32; l++) QhT[(size_t)l * NPIX + i] = (__bf16)0.0f;
    const float cs = (-0.5f / 9.0f) * L2E;
    float sx = 0.f, sy = 0.f;
    int xa = max(0, x - RAD), xb = min(WW - 1, x + RAD);
    int ya = max(0, y - RAD), yb = min(WW - 1, y + RAD);
    for (int t = xa; t <= xb; t++) { float dx = (float)(x - t); sx += fexp2(cs * dx * dx); }
    for (int t = ya; t <= yb; t++) { float dy = (float)(y - t); sy += fexp2(cs * dy * dy); }
    norm_s[i] = 1.0f / (sx * sy + 1e-8f);
}

// ---------- fold 21x21 matrices ----------
__global__ __launch_bounds__(448) void matK(const float* __restrict__ Cm, const float* __restrict__ Wsm,
                                            const float* __restrict__ Wbm,
                                            float* __restrict__ Ms, float* __restrict__ Mb) {
    int t = threadIdx.x;
    if (t >= NL * NL) return;
    int l = t / NL, p = t - l * NL;
    float a = 0.f, b = 0.f;
    for (int m = 0; m < NL; m++) {
        float c = Cm[l * NL + m];
        a = fmaf(c, Wsm[m * NL + p], a);
        b = fmaf(c, Wbm[m * NL + p], b);
    }
    Ms[t] = a; Mb[t] = b;
}

// ---------- iter-0: softmax + fused x-filter (row-block: 192 thr = 2 full rows) ----------
__global__ __launch_bounds__(192) void smaxX0(const float* __restrict__ cur,
                                              __bf16* __restrict__ QhT, float* __restrict__ S1) {
    __shared__ float sqx[NL][194];
    __shared__ float wt[33];
    int t = threadIdx.x;
    if (t < 33) { float d = (float)(t - RAD); wt[t] = fexp2((-0.5f / 9.0f) * L2E * d * d); }
    int i = blockIdx.x * 192 + t;
    float v[NL]; float m = -1e30f;
    #pragma unroll
    for (int l = 0; l < NL; l++) { v[l] = cur[l * NPIX + i]; m = fmaxf(m, v[l]); }
    float s = 0.f;
    #pragma unroll
    for (int l = 0; l < NL; l++) { v[l] = fexp2((v[l] - m) * L2E); s += v[l]; }
    float inv = 1.0f / s;
    #pragma unroll
    for (int l = 0; l < NL; l++) {
        float q = v[l] * inv;
        QhT[(size_t)l * NPIX + i] = (__bf16)q;
        sqx[l][t] = q;
    }
    __syncthreads();
    int row = t / WW, x = t - row * WW;
    int gy = blockIdx.x * 2 + row;
    for (int l = 0; l < NL; l++) {
        float acc = 0.f;
        #pragma unroll
        for (int d = 0; d < 33; d++) {
            int x2 = x - RAD + d;
            if ((unsigned)x2 < WW) acc = fmaf(wt[d], sqx[l][row * WW + x2], acc);
        }
        S1[l * NPIX + gy * WW + x] = acc;
    }
}

// ---------- spatial y-pass: truncated separable Gaussian, one output/thread ----------
__global__ __launch_bounds__(256) void spatY(const float* __restrict__ S1, const float* __restrict__ norm_s,
                                             float* __restrict__ Sp) {
    __shared__ float wt[33];
    int t = threadIdx.x;
    if (t < 33) { float d = (float)(t - RAD); wt[t] = fexp2((-0.5f / 9.0f) * L2E * d * d); }
    __syncthreads();
    int tid = blockIdx.x * 256 + t;                 // NL*NPIX exact (756 blocks)
    int l = tid / NPIX, rem = tid - l * NPIX;
    int y1 = rem / WW, x = rem - y1 * WW;
    const float* col = S1 + l * NPIX + x;
    float acc = 0.f;
    #pragma unroll
    for (int d = 0; d < 33; d++) {
        int y2 = y1 - RAD + d;
        if ((unsigned)y2 < WW) acc = fmaf(wt[d], col[y2 * WW], acc);
    }
    Sp[tid] = acc * norm_s[rem];
}

// ---------- bilateral, attention-style: dot-MFMA -> exp2 -> in-register PV MFMA ----------
__global__ __launch_bounds__(128, 4) void bilatM(const __bf16* __restrict__ QhT,
                                                 const __bf16* __restrict__ FiT8,
                                                 const __bf16* __restrict__ Fj8,
                                                 float* __restrict__ part, int njc) {
    __shared__ __bf16 sQ[2][32][72];    // 144B rows (16B-aligned reads)
    __shared__ __bf16 sFj[2][64][24];   // 48B rows
    int tid = threadIdx.x;
    int lane = tid & 63;
    int n = lane & 31, kb = lane >> 5;
    int jc = blockIdx.y;
    int w = tid >> 6;
    int ibase = blockIdx.x * 64 + w * 32;

    bf16x8 b1 = *reinterpret_cast<const bf16x8*>(FiT8 + (size_t)(ibase + n) * 16 + kb * 8);

    int qr = tid >> 2, qc = tid & 3;          // sQ: row qr, float4 chunks qc, qc+4
    int fr = tid >> 1, fh = tid & 1;          // sFj: row fr, half fh
    int jbeg = jc * njc;
    int nst = njc / 64;
    const __bf16* qsrc = QhT + (size_t)qr * NPIX + jbeg;
    const __bf16* fsrc = Fj8 + (size_t)jbeg * 16;

    float4 gq0 = *reinterpret_cast<const float4*>(qsrc + qc * 8);
    float4 gq1 = *reinterpret_cast<const float4*>(qsrc + (qc + 4) * 8);
    float4 gf  = *reinterpret_cast<const float4*>(fsrc + fr * 16 + fh * 8);
    *reinterpret_cast<float4*>(&sQ[0][qr][qc * 8])       = gq0;
    *reinterpret_cast<float4*>(&sQ[0][qr][(qc + 4) * 8]) = gq1;
    *reinterpret_cast<float4*>(&sFj[0][fr][fh * 8])      = gf;

    f32x16 acc = {};
    const f32x16 z = {};
    int cur = 0;
    for (int s = 0; s < nst; s++) {
        __syncthreads();
        bool pf = (s + 1 < nst);
        if (pf) {
            int jo = (s + 1) * 64;
            gq0 = *reinterpret_cast<const float4*>(qsrc + jo + qc * 8);
            gq1 = *reinterpret_cast<const float4*>(qsrc + jo + (qc + 4) * 8);
            gf  = *reinterpret_cast<const float4*>(fsrc + (size_t)(jo + fr) * 16 + fh * 8);
        }
        #pragma unroll
        for (int t = 0; t < 2; t++) {
            int t32 = t * 32;
            bf16x8 a1 = *reinterpret_cast<const bf16x8*>(&sFj[cur][t32 + n][kb * 8]);
            f32x16 d = __builtin_amdgcn_mfma_f32_32x32x16_bf16(a1, b1, z, 0, 0, 0);
            float e[16];
            #pragma unroll
            for (int q = 0; q < 16; q++) e[q] = fexp2(d[q]);
            #pragma unroll
            for (int h = 0; h < 2; h++) {
                unsigned w0 = pkbf(e[8*h+0], e[8*h+1]);
                unsigned w1 = pkbf(e[8*h+2], e[8*h+3]);
                unsigned w2 = pkbf(e[8*h+4], e[8*h+5]);
                unsigned w3 = pkbf(e[8*h+6], e[8*h+7]);
                asm volatile("v_permlane32_swap_b32 %0, %1" : "+v"(w0), "+v"(w2));
                asm volatile("v_permlane32_swap_b32 %0, %1" : "+v"(w1), "+v"(w3));
                union { int4 u4; bf16x8 h8; } bb;
                bb.u4 = make_int4(w0, w1, w2, w3);
                bf16x8 qa = *reinterpret_cast<const bf16x8*>(&sQ[cur][n][t32 + h * 16 + kb * 8]);
                acc = __builtin_amdgcn_mfma_f32_32x32x16_bf16(qa, bb.h8, acc, 0, 0, 0);
            }
        }
        if (pf) {
            int nx = cur ^ 1;
            *reinterpret_cast<float4*>(&sQ[nx][qr][qc * 8])       = gq0;
            *reinterpret_cast<float4*>(&sQ[nx][qr][(qc + 4) * 8]) = gq1;
            *reinterpret_cast<float4*>(&sFj[nx][fr][fh * 8])      = gf;
        }
        cur ^= 1;
    }
    float* p = part + (size_t)jc * 22 * NPIX + ibase + n;
    #pragma unroll
    for (int q = 0; q < 16; q++) {
        int l = (q & 3) + 8 * (q >> 2) + 4 * kb;   // verified C/D row map
        if (l < 22) p[(size_t)l * NPIX] = acc[q];
    }
}

// ---------- reduce j-chunks (22 rows incl. denominator) ----------
__global__ __launch_bounds__(256) void bredK(const float* __restrict__ part, float* __restrict__ Bl, int js) {
    int t = blockIdx.x * 256 + threadIdx.x;   // 22*NPIX exact (792 blocks)
    float a = 0.f;
    for (int jc = 0; jc < js; jc++) a += part[(size_t)jc * 22 * NPIX + t];
    Bl[t] = a;
}

// ---------- combine + softmax + fused x-filter (row-block: 192 thr = 2 rows) ----------
__global__ __launch_bounds__(192) void combX(const float* __restrict__ Sp, const float* __restrict__ Bl,
                                             const float* __restrict__ Ms, const float* __restrict__ Mb,
                                             const float* __restrict__ unary, float* __restrict__ outp,
                                             __bf16* __restrict__ QhT, float* __restrict__ S1, int wq) {
    __shared__ float sMs[NL * NL], sMb[NL * NL];
    __shared__ float sqx[NL][194];
    __shared__ float wt[33];
    int t = threadIdx.x;
    for (int k = t; k < NL * NL; k += 192) { sMs[k] = Ms[k]; sMb[k] = Mb[k]; }
    if (t < 33) { float d = (float)(t - RAD); wt[t] = fexp2((-0.5f / 9.0f) * L2E * d * d); }
    __syncthreads();
    int i = blockIdx.x * 192 + t;
    float inv = 1.0f / (Bl[(size_t)21 * NPIX + i] + 1e-8f);
    float sp[NL], bl[NL], v[NL];
    #pragma unroll
    for (int p = 0; p < NL; p++) { sp[p] = Sp[p * NPIX + i]; bl[p] = Bl[p * NPIX + i] * inv; }
    #pragma unroll
    for (int l = 0; l < NL; l++) {
        float a = unary[l * NPIX + i];
        #pragma unroll
        for (int p = 0; p < NL; p++) {
            a = fmaf(sMs[l * NL + p], sp[p], a);
            a = fmaf(sMb[l * NL + p], bl[p], a);
        }
        outp[l * NPIX + i] = a;
        v[l] = a;
    }
    if (!wq) return;
    float m = -1e30f;
    #pragma unroll
    for (int l = 0; l < NL; l++) m = fmaxf(m, v[l]);
    float s = 0.f;
    #pragma unroll
    for (int l = 0; l < NL; l++) { v[l] = fexp2((v[l] - m) * L2E); s += v[l]; }
    float qi = 1.0f / s;
    #pragma unroll
    for (int l = 0; l < NL; l++) {
        float q = v[l] * qi;
        QhT[(size_t)l * NPIX + i] = (__bf16)q;
        sqx[l][t] = q;
    }
    __syncthreads();
    int row = t / WW, x = t - row * WW;
    int gy = blockIdx.x * 2 + row;
    for (int l = 0; l < NL; l++) {
        float acc = 0.f;
        #pragma unroll
        for (int d = 0; d < 33; d++) {
            int x2 = x - RAD + d;
            if ((unsigned)x2 < WW) acc = fmaf(wt[d], sqx[l][row * WW + x2], acc);
        }
        S1[l * NPIX + gy * WW + x] = acc;
    }
}

extern "C" void kernel_launch(void* const* d_in, const int* in_sizes, int n_in,
                              void* d_out, int out_size, void* d_ws, size_t ws_size,
                              hipStream_t stream) {
    const float* img   = (const float*)d_in[0];
    const float* logit = (const float*)d_in[1];
    const float* Wsm   = (const float*)d_in[2];
    const float* Wbm   = (const float*)d_in[3];
    const float* Cm    = (const float*)d_in[4];
    float* out = (float*)d_out;
    float* ws  = (float*)d_ws;

    // workspace layout (float offsets)
    __bf16* FiT8  = (__bf16*)ws;              // [0, 73728)
    __bf16* Fj8   = (__bf16*)(ws + 73728);    // [73728, 147456)
    float* S1     = ws + 147456;              // [147456, 340992)
    float* Sp     = S1 + NL * NPIX;           // [340992, 534528)
    float* Bl     = Sp + NL * NPIX;           // [534528, 737280) (22 rows)
    float* norm_s = Bl + 22 * NPIX;           // [737280, 746496)
    float* Ms     = norm_s + NPIX;            // [746496, 746944)
    float* Mb     = Ms + 448;                 // [746944, 747392)
    __bf16* QhT   = (__bf16*)(Mb + 448);      // [747392, 894848)  32*NPIX bf16 = 147456 floats
    float* part   = ws + 894848;              // [894848, ...)  js*22*NPIX  (AFTER QhT end!)

    int js = JS;
    while (js > 1 && (894848ull + (size_t)js * 22 * NPIX) * 4 > ws_size) js >>= 1;
    int njc = NPIX / js;

    featK<<<36, 256, 0, stream>>>(img, FiT8, Fj8, norm_s, QhT);
    matK<<<1, 448, 0, stream>>>(Cm, Wsm, Wbm, Ms, Mb);
    smaxX0<<<48, 192, 0, stream>>>(logit, QhT, S1);
    for (int it = 0; it < 5; ++it) {
        spatY<<<756, 256, 0, stream>>>(S1, norm_s, Sp);
        bilatM<<<dim3(NPIX / 64, js), 128, 0, stream>>>(QhT, FiT8, Fj8, part, njc);
        bredK<<<792, 256, 0, stream>>>(part, Bl, js);
        combX<<<48, 192, 0, stream>>>(Sp, Bl, Ms, Mb, logit, out, QhT, S1, it < 4 ? 1 : 0);
    }
}

// Round 10
// 214.010 us; speedup vs baseline: 1.7271x; 1.7271x over previous
//
#include <hip/hip_runtime.h>

#define NPIX 9216
#define NL   21
#define WW   96
#define RAD  16
#define JS   16
#define NJC  576            // NPIX / JS
#define NST  9              // NJC / 64
#define NIB  72             // NPIX / 128 i-blocks
#define NBIL (NIB * JS)     // 1152 bilat blocks
#define NSPY 756            // NL*NPIX / 256 spatY blocks
#define L2E  1.44269504088896340736f

typedef __bf16 bf16x8 __attribute__((ext_vector_type(8)));
typedef float  f32x16 __attribute__((ext_vector_type(16)));

__device__ __forceinline__ float fexp2(float x) { return __builtin_amdgcn_exp2f(x); }
__device__ __forceinline__ unsigned pkbf(float lo, float hi) {
    unsigned r;
    asm("v_cvt_pk_bf16_f32 %0, %1, %2" : "=v"(r) : "v"(lo), "v"(hi));
    return r;
}

// ---------- prep: bf16 feature fragments + truncated spatial norm + QhT const rows + zero Bl ----------
// Fj8[j][16] = [fj*L2E x5, sj', 1, 0...]   (A-side of dot MFMA)
// FiT8[i][16] = [fi x5, -1, -si', 0...]    (B-side)  =>  D = L2E*fi.fj - sj' - si'
__global__ __launch_bounds__(256) void featK(const float* __restrict__ img,
                                             __bf16* __restrict__ FiT8, __bf16* __restrict__ Fj8,
                                             float* __restrict__ norm_s, __bf16* __restrict__ QhT,
                                             float* __restrict__ Bl) {
    int i = blockIdx.x * 256 + threadIdx.x;
    if (i >= NPIX) return;
    int y = i / WW, x = i - y * WW;
    float f0 = (float)x * (1.0f / 160.0f);
    float f1 = (float)y * (1.0f / 160.0f);
    float f2 = img[0 * NPIX + i] * (1.0f / 3.0f);
    float f3 = img[1 * NPIX + i] * (1.0f / 3.0f);
    float f4 = img[2 * NPIX + i] * (1.0f / 3.0f);
    float st = 0.5f * (f0*f0 + f1*f1 + f2*f2 + f3*f3 + f4*f4) * L2E;
    __bf16* a = Fj8 + (size_t)i * 16;
    __bf16* b = FiT8 + (size_t)i * 16;
    a[0]=(__bf16)(f0*L2E); a[1]=(__bf16)(f1*L2E); a[2]=(__bf16)(f2*L2E);
    a[3]=(__bf16)(f3*L2E); a[4]=(__bf16)(f4*L2E); a[5]=(__bf16)st; a[6]=(__bf16)1.0f;
    b[0]=(__bf16)f0; b[1]=(__bf16)f1; b[2]=(__bf16)f2; b[3]=(__bf16)f3; b[4]=(__bf16)f4;
    b[5]=(__bf16)-1.0f; b[6]=(__bf16)(-st);
    #pragma unroll
    for (int k = 7; k < 16; k++) { a[k] = (__bf16)0.0f; b[k] = (__bf16)0.0f; }
    QhT[(size_t)21 * NPIX + i] = (__bf16)1.0f;
    #pragma unroll
    for (int l = 22; l < 32; l++) QhT[(size_t)l * NPIX + i] = (__bf16)0.0f;
    #pragma unroll
    for (int l = 0; l < 22; l++) Bl[(size_t)l * NPIX + i] = 0.0f;
    const float cs = (-0.5f / 9.0f) * L2E;
    float sx = 0.f, sy = 0.f;
    int xa = max(0, x - RAD), xb = min(WW - 1, x + RAD);
    int ya = max(0, y - RAD), yb = min(WW - 1, y + RAD);
    for (int t = xa; t <= xb; t++) { float dx = (float)(x - t); sx += fexp2(cs * dx * dx); }
    for (int t = ya; t <= yb; t++) { float dy = (float)(y - t); sy += fexp2(cs * dy * dy); }
    norm_s[i] = 1.0f / (sx * sy + 1e-8f);
}

// ---------- fold 21x21 matrices ----------
__global__ __launch_bounds__(448) void matK(const float* __restrict__ Cm, const float* __restrict__ Wsm,
                                            const float* __restrict__ Wbm,
                                            float* __restrict__ Ms, float* __restrict__ Mb) {
    int t = threadIdx.x;
    if (t >= NL * NL) return;
    int l = t / NL, p = t - l * NL;
    float a = 0.f, b = 0.f;
    for (int m = 0; m < NL; m++) {
        float c = Cm[l * NL + m];
        a = fmaf(c, Wsm[m * NL + p], a);
        b = fmaf(c, Wbm[m * NL + p], b);
    }
    Ms[t] = a; Mb[t] = b;
}

// ---------- softmax over labels (iter 0 only) ----------
__global__ __launch_bounds__(256) void softmaxK(const float* __restrict__ cur,
                                                __bf16* __restrict__ QhT, float* __restrict__ Qlm) {
    int i = blockIdx.x * 256 + threadIdx.x;
    if (i >= NPIX) return;
    float v[NL]; float m = -1e30f;
    #pragma unroll
    for (int l = 0; l < NL; l++) { v[l] = cur[l * NPIX + i]; m = fmaxf(m, v[l]); }
    float s = 0.f;
    #pragma unroll
    for (int l = 0; l < NL; l++) { v[l] = fexp2((v[l] - m) * L2E); s += v[l]; }
    float inv = 1.0f / s;
    #pragma unroll
    for (int l = 0; l < NL; l++) {
        float q = v[l] * inv;
        Qlm[l * NPIX + i] = q;
        QhT[(size_t)l * NPIX + i] = (__bf16)q;
    }
}

// ---------- spatial x-pass: truncated separable Gaussian, one output/thread ----------
__global__ __launch_bounds__(256) void spatX(const float* __restrict__ Qlm, float* __restrict__ S1) {
    __shared__ float wt[33];
    int t = threadIdx.x;
    if (t < 33) { float d = (float)(t - RAD); wt[t] = fexp2((-0.5f / 9.0f) * L2E * d * d); }
    __syncthreads();
    int tid = blockIdx.x * 256 + t;                 // NL*NPIX exact (756 blocks)
    int l = tid / NPIX, rem = tid - l * NPIX;
    int y = rem / WW, x1 = rem - y * WW;
    const float* row = Qlm + l * NPIX + y * WW;
    float acc = 0.f;
    #pragma unroll
    for (int d = 0; d < 33; d++) {
        int x2 = x1 - RAD + d;
        if ((unsigned)x2 < WW) acc = fmaf(wt[d], row[x2], acc);
    }
    S1[tid] = acc;
}

// ---------- fused: bilat (blocks 0..NBIL-1) | spatY (blocks NBIL..NBIL+NSPY-1) ----------
// bilat: 4 waves x 32 i each = 128 i/block; attention-style dot-MFMA -> exp2 -> PV MFMA;
//        accumulates into Bl via device-scope atomicAdd (Bl pre-zeroed).
// spatY: truncated y-filter, one output/thread.
__global__ __launch_bounds__(256) void fusedYB(const __bf16* __restrict__ QhT,
                                               const __bf16* __restrict__ FiT8,
                                               const __bf16* __restrict__ Fj8,
                                               float* __restrict__ Bl,
                                               const float* __restrict__ S1,
                                               const float* __restrict__ norm_s,
                                               float* __restrict__ Sp) {
    __shared__ __bf16 sQ[2][32][72];    // 9216 B
    __shared__ __bf16 sFj[2][64][24];   // 6144 B
    __shared__ float wt[33];
    int t = threadIdx.x;

    if (blockIdx.x >= NBIL) {
        // ---- spatY branch ----
        if (t < 33) { float d = (float)(t - RAD); wt[t] = fexp2((-0.5f / 9.0f) * L2E * d * d); }
        __syncthreads();
        int tid = (blockIdx.x - NBIL) * 256 + t;
        int l = tid / NPIX, rem = tid - l * NPIX;
        int y1 = rem / WW, x = rem - y1 * WW;
        const float* col = S1 + l * NPIX + x;
        float acc = 0.f;
        #pragma unroll
        for (int d = 0; d < 33; d++) {
            int y2 = y1 - RAD + d;
            if ((unsigned)y2 < WW) acc = fmaf(wt[d], col[y2 * WW], acc);
        }
        Sp[tid] = acc * norm_s[rem];
        return;
    }

    // ---- bilat branch ----
    int lane = t & 63;
    int w = t >> 6;
    int n = lane & 31, kb = lane >> 5;
    int jc = blockIdx.x / NIB;
    int ib = blockIdx.x - jc * NIB;
    int ibase = ib * 128 + w * 32;

    bf16x8 b1 = *reinterpret_cast<const bf16x8*>(FiT8 + (size_t)(ibase + n) * 16 + kb * 8);

    // staging roles (256 threads)
    int qr = t >> 3, qc = t & 7;          // sQ: 32 rows x 8 float4 chunks
    int fr = t >> 1, fh = t & 1;          // sFj: 64 rows x 2 float4 (threads < 128)
    int jbeg = jc * NJC;
    const __bf16* qsrc = QhT + (size_t)qr * NPIX + jbeg;
    const __bf16* fsrc = Fj8 + (size_t)jbeg * 16;

    float4 gq = *reinterpret_cast<const float4*>(qsrc + qc * 8);
    float4 gf;
    if (t < 128) gf = *reinterpret_cast<const float4*>(fsrc + fr * 16 + fh * 8);
    *reinterpret_cast<float4*>(&sQ[0][qr][qc * 8]) = gq;
    if (t < 128) *reinterpret_cast<float4*>(&sFj[0][fr][fh * 8]) = gf;

    f32x16 acc = {};
    const f32x16 z = {};
    int cur = 0;
    for (int s = 0; s < NST; s++) {
        __syncthreads();
        bool pf = (s + 1 < NST);
        if (pf) {
            int jo = (s + 1) * 64;
            gq = *reinterpret_cast<const float4*>(qsrc + jo + qc * 8);
            if (t < 128) gf = *reinterpret_cast<const float4*>(fsrc + (size_t)(jo + fr) * 16 + fh * 8);
        }
        #pragma unroll
        for (int t2 = 0; t2 < 2; t2++) {
            int t32 = t2 * 32;
            bf16x8 a1 = *reinterpret_cast<const bf16x8*>(&sFj[cur][t32 + n][kb * 8]);
            f32x16 d = __builtin_amdgcn_mfma_f32_32x32x16_bf16(a1, b1, z, 0, 0, 0);
            float e[16];
            #pragma unroll
            for (int q = 0; q < 16; q++) e[q] = fexp2(d[q]);
            #pragma unroll
            for (int h = 0; h < 2; h++) {
                unsigned w0 = pkbf(e[8*h+0], e[8*h+1]);
                unsigned w1 = pkbf(e[8*h+2], e[8*h+3]);
                unsigned w2 = pkbf(e[8*h+4], e[8*h+5]);
                unsigned w3 = pkbf(e[8*h+6], e[8*h+7]);
                asm volatile("v_permlane32_swap_b32 %0, %1" : "+v"(w0), "+v"(w2));
                asm volatile("v_permlane32_swap_b32 %0, %1" : "+v"(w1), "+v"(w3));
                union { int4 u4; bf16x8 h8; } bb;
                bb.u4 = make_int4(w0, w1, w2, w3);
                bf16x8 qa = *reinterpret_cast<const bf16x8*>(&sQ[cur][n][t32 + h * 16 + kb * 8]);
                acc = __builtin_amdgcn_mfma_f32_32x32x16_bf16(qa, bb.h8, acc, 0, 0, 0);
            }
        }
        if (pf) {
            int nx = cur ^ 1;
            *reinterpret_cast<float4*>(&sQ[nx][qr][qc * 8]) = gq;
            if (t < 128) *reinterpret_cast<float4*>(&sFj[nx][fr][fh * 8]) = gf;
        }
        cur ^= 1;
    }
    int gi = ibase + n;
    #pragma unroll
    for (int q = 0; q < 16; q++) {
        int l = (q & 3) + 8 * (q >> 2) + 4 * kb;   // verified C/D row map
        if (l < 22) atomicAdd(&Bl[(size_t)l * NPIX + gi], acc[q]);
    }
}

// ---------- combine + fused softmax + re-zero Bl for next iteration ----------
__global__ __launch_bounds__(256) void combZ(const float* __restrict__ Sp, float* __restrict__ Bl,
                                             const float* __restrict__ Ms, const float* __restrict__ Mb,
                                             const float* __restrict__ unary, float* __restrict__ outp,
                                             __bf16* __restrict__ QhT, float* __restrict__ Qlm, int wq) {
    __shared__ float sMs[NL * NL], sMb[NL * NL];
    int t = threadIdx.x;
    for (int k = t; k < NL * NL; k += 256) { sMs[k] = Ms[k]; sMb[k] = Mb[k]; }
    __syncthreads();
    int i = blockIdx.x * 256 + t;
    if (i >= NPIX) return;
    float inv = 1.0f / (Bl[(size_t)21 * NPIX + i] + 1e-8f);
    float sp[NL], bl[NL], v[NL];
    #pragma unroll
    for (int p = 0; p < NL; p++) { sp[p] = Sp[p * NPIX + i]; bl[p] = Bl[p * NPIX + i] * inv; }
    #pragma unroll
    for (int l = 0; l < 22; l++) Bl[(size_t)l * NPIX + i] = 0.0f;   // ready for next bilat
    #pragma unroll
    for (int l = 0; l < NL; l++) {
        float a = unary[l * NPIX + i];
        #pragma unroll
        for (int p = 0; p < NL; p++) {
            a = fmaf(sMs[l * NL + p], sp[p], a);
            a = fmaf(sMb[l * NL + p], bl[p], a);
        }
        outp[l * NPIX + i] = a;
        v[l] = a;
    }
    if (!wq) return;
    float m = -1e30f;
    #pragma unroll
    for (int l = 0; l < NL; l++) m = fmaxf(m, v[l]);
    float s = 0.f;
    #pragma unroll
    for (int l = 0; l < NL; l++) { v[l] = fexp2((v[l] - m) * L2E); s += v[l]; }
    float qi = 1.0f / s;
    #pragma unroll
    for (int l = 0; l < NL; l++) {
        float q = v[l] * qi;
        Qlm[l * NPIX + i] = q;
        QhT[(size_t)l * NPIX + i] = (__bf16)q;
    }
}

extern "C" void kernel_launch(void* const* d_in, const int* in_sizes, int n_in,
                              void* d_out, int out_size, void* d_ws, size_t ws_size,
                              hipStream_t stream) {
    const float* img   = (const float*)d_in[0];
    const float* logit = (const float*)d_in[1];
    const float* Wsm   = (const float*)d_in[2];
    const float* Wbm   = (const float*)d_in[3];
    const float* Cm    = (const float*)d_in[4];
    float* out = (float*)d_out;
    float* ws  = (float*)d_ws;

    // workspace layout (float offsets)
    __bf16* FiT8  = (__bf16*)ws;              // [0, 73728)
    __bf16* Fj8   = (__bf16*)(ws + 73728);    // [73728, 147456)
    float* Qlm    = ws + 147456;              // [147456, 340992)
    float* S1     = ws + 340992;              // [340992, 534528)
    float* Sp     = ws + 534528;              // [534528, 728064)
    float* Bl     = ws + 728064;              // [728064, 930816)  22 rows
    float* norm_s = ws + 930816;              // [930816, 940032)
    float* Ms     = ws + 940032;              // [940032, 940480)
    float* Mb     = ws + 940480;              // [940480, 940928)
    __bf16* QhT   = (__bf16*)(ws + 940928);   // [940928, 1088384)  32*NPIX bf16 = 147456 floats

    featK<<<36, 256, 0, stream>>>(img, FiT8, Fj8, norm_s, QhT, Bl);
    matK<<<1, 448, 0, stream>>>(Cm, Wsm, Wbm, Ms, Mb);
    softmaxK<<<36, 256, 0, stream>>>(logit, QhT, Qlm);
    spatX<<<756, 256, 0, stream>>>(Qlm, S1);
    for (int it = 0; it < 5; ++it) {
        fusedYB<<<NBIL + NSPY, 256, 0, stream>>>(QhT, FiT8, Fj8, Bl, S1, norm_s, Sp);
        combZ<<<36, 256, 0, stream>>>(Sp, Bl, Ms, Mb, logit, out, QhT, Qlm, it < 4 ? 1 : 0);
        if (it < 4) spatX<<<756, 256, 0, stream>>>(Qlm, S1);
    }
}